// Round 17
// baseline (46.334 us; speedup 1.0000x reference)
//
#include <hip/hip_runtime.h>
#include <hip/hip_bf16.h>
#include <math.h>

// BayesianSkipgram: V=100000, E=256, D=128, B=8192, C=10
// v17 = v15 with bsg_h at BT1=4 (half tile):
//   LDS 25.3 KB/block -> 4 blocks/CU (32-wave cap) vs 3 at BT1=8.
//   6 coalesced 1KB-row loads/thread, ONE barrier, 4ch x 3mt MFMA.
//   Epilogue mapping: slot c = 4*mt+lg, b = q; cross-lg shfl reduce.
//   bsg_kl (BT2=32), k_cvt: unchanged from v15.
// ws layout (ushort): M_bf [0,32768), U|W_bf [32768,98304), h [98304,+2M).

#define CTXN  10
#define DDIM  128
#define WS_M   0
#define WS_UW  32768
#define WS_H   98304

typedef short bf16x8 __attribute__((ext_vector_type(8)));
typedef float f32x4  __attribute__((ext_vector_type(4)));

__device__ __forceinline__ uint2 cvt4(float4 v) {
    union { __hip_bfloat162 h2; unsigned u; } a, b;
    a.h2 = __float22bfloat162_rn(make_float2(v.x, v.y));
    b.h2 = __float22bfloat162_rn(make_float2(v.z, v.w));
    return make_uint2(a.u, b.u);
}

__device__ __forceinline__ float softplusf(float v) {
    return fmaxf(v, 0.0f) + log1pf(expf(-fabsf(v)));
}

// ---------------- kernel 0: weight fp32 -> bf16 ----------------
__global__ __launch_bounds__(256) void k_cvt(
    const float* __restrict__ M_w, const float* __restrict__ U_w,
    const float* __restrict__ W_w, unsigned short* __restrict__ ws)
{
    int which = blockIdx.x >> 5;                       // 0:M 1:U 2:W
    int i = ((blockIdx.x & 31) << 8) | threadIdx.x;    // float4 idx 0..8191
    const float* src = (which == 0) ? M_w : (which == 1) ? U_w : W_w;
    float4 v = ((const float4*)src)[i];
    *(uint2*)&ws[which * 32768 + i * 4] = cvt4(v);
}

// ---------------- kernel 1: gather + emb@M_w^T + relu-sum -> h ----------------
#define BT1   4
#define ROWSP 48              // rows r = c*4+b (c=0..10, b=0..3); 44..47 garbage (c=11)
#define LP2   264             // A row stride (ushort): 528 B

__global__ __launch_bounds__(512, 8) void bsg_h(
    const int* __restrict__ x, const int* __restrict__ ctx,
    const float* __restrict__ W_emb, const float* __restrict__ M_b,
    const unsigned short* __restrict__ wsr, unsigned short* __restrict__ hws)
{
    __shared__ __align__(16) unsigned short A_s[ROWSP * LP2];   // 25344 B
    __shared__ int idx_s[ROWSP];

    const int tid  = threadIdx.x;
    const int b0   = blockIdx.x * BT1;
    const int w    = tid >> 6;       // wave 0..7 owns d-cols 16w..16w+15
    const int lane = tid & 63;
    const int l15  = lane & 15;
    const int lg   = lane >> 4;

    if (tid < ROWSP) {
        int c = tid >> 2, b = b0 + (tid & 3);
        idx_s[tid] = (c >= 11) ? 0 : ((c == 0) ? x[b] : ctx[b * CTXN + (c - 1)]);
    }
    __syncthreads();

    // ---- single-shot staging: 48 rows x 64 float4 = 3072 = 6 x 512 ----
    // step s: wave rs stages row rs + 8s (wave-per-row perfect coalescing)
    const int rs = tid >> 6;
    const int qs = tid & 63;
    const float4* We = (const float4*)W_emb;

    float4 rr[6];
#pragma unroll
    for (int s = 0; s < 6; ++s)
        rr[s] = We[(size_t)idx_s[rs + 8 * s] * 64 + qs];
#pragma unroll
    for (int s = 0; s < 6; ++s)
        *(uint2*)&A_s[(rs + 8 * s) * LP2 + 4 * qs] = cvt4(rr[s]);
    __syncthreads();   // the only phase-1 barrier

    // ---- MFMA: 4 k-chunks x 3 M-tiles, M-frags from L2-hot bf16 ws ----
    const unsigned short* Mb_bf = wsr + WS_M;   // [128][256] bf16
    const int mrow = 16 * w + l15;
    f32x4 acc[3] = {};
#pragma unroll
    for (int ch = 0; ch < 4; ++ch) {
        bf16x8 m0 = *(const bf16x8*)&Mb_bf[mrow * 256 + 64 * ch + 8 * lg];
        bf16x8 m1 = *(const bf16x8*)&Mb_bf[mrow * 256 + 64 * ch + 32 + 8 * lg];
#pragma unroll
        for (int mt = 0; mt < 3; ++mt) {
            bf16x8 a0 = *(const bf16x8*)&A_s[(16 * mt + l15) * LP2 + 64 * ch + 8 * lg];
            bf16x8 a1 = *(const bf16x8*)&A_s[(16 * mt + l15) * LP2 + 64 * ch + 32 + 8 * lg];
            acc[mt] = __builtin_amdgcn_mfma_f32_16x16x32_bf16(a0, m0, acc[mt], 0, 0, 0);
            acc[mt] = __builtin_amdgcn_mfma_f32_16x16x32_bf16(a1, m1, acc[mt], 0, 0, 0);
        }
    }

    // ---- relu-sum.  acc[mt][q] row = 16mt+4lg+q -> c = 4mt+lg, b = q ----
    // c=0 is (mt=0,lg=0); c=11 garbage is (mt=2,lg=3).
    const int dg = 16 * w + l15;
    const float mb = M_b[dg];
    float h1[4], s[4];
#pragma unroll
    for (int q = 0; q < 4; ++q) {
        float r0 = fmaxf(acc[0][q] + mb, 0.0f);
        float r1 = fmaxf(acc[1][q] + mb, 0.0f);
        float r2 = fmaxf(acc[2][q] + mb, 0.0f);
        h1[q] = r0;                                   // only lg==0's is c=0
        float t = r1;                                 // c = 4+lg, always ctx
        t += (lg == 0) ? 0.0f : r0;                   // c = lg (1..3 for lg>0)
        t += (lg == 3) ? 0.0f : r2;                   // c = 8+lg (garbage if lg==3)
        s[q] = t;
    }
#pragma unroll
    for (int q = 0; q < 4; ++q) {
        float t = s[q];
        t += __shfl_xor(t, 16);
        t += __shfl_xor(t, 32);                       // total over lg0..3
        if (lg == 0) {
            __hip_bfloat16 t1 = __float2bfloat16(10.0f * h1[q]);  // C*relu(Rw)
            __hip_bfloat16 t2 = __float2bfloat16(t);              // sum relu(Rc)
            hws[(size_t)(b0 + q) * 256 + dg]       = *(unsigned short*)&t1;
            hws[(size_t)(b0 + q) * 256 + 128 + dg] = *(unsigned short*)&t2;
        }
    }
}

// ---------------- kernel 2: h @ [U;W]^T + softplus + KL (BT2=32) ----------------
#define BT2  32
#define HLP  264

__global__ __launch_bounds__(512, 4) void bsg_kl(
    const int* __restrict__ x, const float* __restrict__ U_b,
    const float* __restrict__ W_b, const float* __restrict__ pmu,
    const float* __restrict__ psg, const unsigned short* __restrict__ wsr,
    float* __restrict__ out)
{
    __shared__ __align__(16) unsigned short H_s[BT2 * HLP];   // 16896 B
    __shared__ float P_s[BT2 * 8];

    const int tid  = threadIdx.x;
    const int b0   = blockIdx.x * BT2;
    const int w    = tid >> 6;       // wave 0..7 owns d-cols 16w..16w+15
    const int lane = tid & 63;
    const int l15  = lane & 15;
    const int lg   = lane >> 4;
    const int d    = 16 * w + l15;

    // prior gathers issued upfront (x[] L2-hot); consumed only in epilogue
    float pm[2][4], ps[2][4];
#pragma unroll
    for (int mt = 0; mt < 2; ++mt)
#pragma unroll
        for (int q = 0; q < 4; ++q) {
            int xb = x[b0 + 16 * mt + 4 * lg + q];
            pm[mt][q] = pmu[(size_t)xb * DDIM + d];
            ps[mt][q] = psg[(size_t)xb * DDIM + d];
        }

    // h tile copy: 512 threads x 2 x 16B = whole [32][256] tile
    const unsigned short* hws = wsr + WS_H;
#pragma unroll
    for (int s = 0; s < 2; ++s) {
        int it = tid + 512 * s;
        int r = it >> 5, q = it & 31;
        *(uint4*)&H_s[r * HLP + 8 * q] =
            *(const uint4*)&hws[(size_t)(b0 + r) * 256 + 8 * q];
    }
    __syncthreads();

    const unsigned short* UWb = wsr + WS_UW;    // [256][256]: 0..127=U, 128..255=W
    f32x4 acc2[2][2] = {};                      // [mtile][0=mu,1=presig]
#pragma unroll
    for (int ks = 0; ks < 8; ++ks) {
        bf16x8 bu = *(const bf16x8*)&UWb[d * 256 + 32 * ks + 8 * lg];
        bf16x8 bw = *(const bf16x8*)&UWb[(128 + d) * 256 + 32 * ks + 8 * lg];
#pragma unroll
        for (int mt = 0; mt < 2; ++mt) {
            bf16x8 hf = *(const bf16x8*)&H_s[(16 * mt + l15) * HLP + 32 * ks + 8 * lg];
            acc2[mt][0] = __builtin_amdgcn_mfma_f32_16x16x32_bf16(hf, bu, acc2[mt][0], 0, 0, 0);
            acc2[mt][1] = __builtin_amdgcn_mfma_f32_16x16x32_bf16(hf, bw, acc2[mt][1], 0, 0, 0);
        }
    }

    const float ub = U_b[d], wb = W_b[d];
#pragma unroll
    for (int mt = 0; mt < 2; ++mt) {
#pragma unroll
        for (int q = 0; q < 4; ++q) {
            int rb = 16 * mt + 4 * lg + q;      // batch row (C/D: row=4lg+q, col=l15)
            float mu = acc2[mt][0][q] + ub;
            float sg = softplusf(acc2[mt][1][q] + wb);
            float dm = mu - pm[mt][q];
            float p  = ps[mt][q] / sg + dm * dm / sg + logf(sg) - logf(ps[mt][q]);
            p += __shfl_xor(p, 1);
            p += __shfl_xor(p, 2);
            p += __shfl_xor(p, 4);
            p += __shfl_xor(p, 8);
            if (l15 == 0) P_s[rb * 8 + w] = p;
        }
    }
    __syncthreads();
    if (tid < BT2) {
        float s = 0.0f;
#pragma unroll
        for (int k = 0; k < 8; ++k) s += P_s[tid * 8 + k];
        out[b0 + tid] = 0.5f * (s - (float)DDIM);
    }
}

extern "C" void kernel_launch(void* const* d_in, const int* in_sizes, int n_in,
                              void* d_out, int out_size, void* d_ws, size_t ws_size,
                              hipStream_t stream) {
    const int*   x     = (const int*)  d_in[0];
    const int*   ctx   = (const int*)  d_in[1];
    const float* W_emb = (const float*)d_in[2];
    const float* M_w   = (const float*)d_in[3];
    const float* M_b   = (const float*)d_in[4];
    const float* U_w   = (const float*)d_in[5];
    const float* U_b   = (const float*)d_in[6];
    const float* W_w   = (const float*)d_in[7];
    const float* W_b   = (const float*)d_in[8];
    const float* pmu   = (const float*)d_in[9];
    const float* psg   = (const float*)d_in[10];
    float* out = (float*)d_out;
    unsigned short* ws = (unsigned short*)d_ws;   // needs >= 4,390,912 bytes

    k_cvt<<<dim3(96), dim3(256), 0, stream>>>(M_w, U_w, W_w, ws);
    bsg_h<<<dim3(8192 / BT1), dim3(512), 0, stream>>>(x, ctx, W_emb, M_b,
                                                      ws, ws + WS_H);
    bsg_kl<<<dim3(8192 / BT2), dim3(512), 0, stream>>>(x, U_b, W_b, pmu, psg,
                                                       ws, out);
}

// Round 18
// 45.208 us; speedup vs baseline: 1.0249x; 1.0249x over previous
//
#include <hip/hip_runtime.h>
#include <hip/hip_bf16.h>
#include <math.h>

// BayesianSkipgram: V=100000, E=256, D=128, B=8192, C=10
// v18 = v15 minus k_cvt (one less launch + drain boundary):
//   bsg_h : per-wave M-fragments loaded fp32 UPFRONT (16 float4, issued
//           before idx chain -> overlap gather; NOT in-loop like v9) and
//           cvt8'd to mreg[8]. Blocks 0..31 also convert U_w/W_w -> bf16
//           into ws (1 float4/thread, overlapped). Staging = v16's 2x6
//           split (peak regs ~75). One barrier. BT1=8.
//   bsg_kl: v15's BT2=32 kernel, reads UW_bf written by bsg_h.
// ws layout (ushort): U|W_bf [0,65536), h [65536, 65536+4194304/2).
// bytes needed: 131072 + 4194304 = 4,325,376.

#define CTXN  10
#define DDIM  128
#define WS_UW  0
#define WS_H   65536

typedef short bf16x8 __attribute__((ext_vector_type(8)));
typedef float f32x4  __attribute__((ext_vector_type(4)));

__device__ __forceinline__ uint2 cvt4(float4 v) {
    union { __hip_bfloat162 h2; unsigned u; } a, b;
    a.h2 = __float22bfloat162_rn(make_float2(v.x, v.y));
    b.h2 = __float22bfloat162_rn(make_float2(v.z, v.w));
    return make_uint2(a.u, b.u);
}

__device__ __forceinline__ bf16x8 cvt8(float4 a, float4 b) {
    union { __hip_bfloat162 h2[4]; bf16x8 v; } u;
    u.h2[0] = __float22bfloat162_rn(make_float2(a.x, a.y));
    u.h2[1] = __float22bfloat162_rn(make_float2(a.z, a.w));
    u.h2[2] = __float22bfloat162_rn(make_float2(b.x, b.y));
    u.h2[3] = __float22bfloat162_rn(make_float2(b.z, b.w));
    return u.v;
}

__device__ __forceinline__ float softplusf(float v) {
    return fmaxf(v, 0.0f) + log1pf(expf(-fabsf(v)));
}

// ---------------- kernel 1: gather + emb@M_w^T + relu-sum -> h ----------------
#define BT1   8
#define ROWSP 96              // rows r = c*8+b (c=0..10); 88..95 garbage
#define LP2   264             // A row stride (ushort): 528 B

__global__ __launch_bounds__(512, 4) void bsg_h(
    const int* __restrict__ x, const int* __restrict__ ctx,
    const float* __restrict__ W_emb, const float* __restrict__ M_w,
    const float* __restrict__ M_b,   const float* __restrict__ U_w,
    const float* __restrict__ W_w,
    unsigned short* __restrict__ ws, unsigned short* __restrict__ hws)
{
    __shared__ __align__(16) unsigned short A_s[ROWSP * LP2];   // 50688 B
    __shared__ int idx_s[ROWSP];

    const int tid  = threadIdx.x;
    const int b0   = blockIdx.x * BT1;
    const int w    = tid >> 6;       // wave 0..7 owns d-cols 16w..16w+15
    const int lane = tid & 63;
    const int l15  = lane & 15;
    const int lg   = lane >> 4;

    // ---- M-fragments fp32 -> registers, issued FIRST (no idx dependency) ----
    const int mrow = 16 * w + l15;
    const float4* Mw4 = (const float4*)M_w;
    bf16x8 mreg[8];
#pragma unroll
    for (int kk = 0; kk < 8; ++kk) {
        float4 a = Mw4[mrow * 64 + 8 * kk + 2 * lg];
        float4 b = Mw4[mrow * 64 + 8 * kk + 2 * lg + 1];
        mreg[kk] = cvt8(a, b);
    }

    // ---- blocks 0..31: convert U_w/W_w -> bf16 ws (1 float4/thread) ----
    if (blockIdx.x < 32) {
        int it = blockIdx.x * 512 + tid;      // 0..16383 = all UW float4s
        int n = it >> 6, q = it & 63;         // row 0..255, float4 col
        const float* src = (n < DDIM) ? U_w : W_w;
        float4 v = ((const float4*)src)[(n & 127) * 64 + q];
        *(uint2*)&ws[WS_UW + n * 256 + 4 * q] = cvt4(v);
    }

    if (tid < ROWSP) {
        int c = tid >> 3, b = b0 + (tid & 7);
        idx_s[tid] = (c >= 11) ? 0 : ((c == 0) ? x[b] : ctx[b * CTXN + (c - 1)]);
    }
    __syncthreads();

    // ---- staging in 2 groups of 6 (wave-per-row coalescing) ----
    const int rs = tid >> 6;
    const int qs = tid & 63;
    const float4* We = (const float4*)W_emb;
    {
        float4 rr[6];
#pragma unroll
        for (int s = 0; s < 6; ++s)
            rr[s] = We[(size_t)idx_s[rs + 8 * s] * 64 + qs];
#pragma unroll
        for (int s = 0; s < 6; ++s)
            *(uint2*)&A_s[(rs + 8 * s) * LP2 + 4 * qs] = cvt4(rr[s]);
#pragma unroll
        for (int s = 6; s < 12; ++s)
            rr[s - 6] = We[(size_t)idx_s[rs + 8 * s] * 64 + qs];
#pragma unroll
        for (int s = 6; s < 12; ++s)
            *(uint2*)&A_s[(rs + 8 * s) * LP2 + 4 * qs] = cvt4(rr[s - 6]);
    }
    __syncthreads();   // the only phase-1 barrier

    // ---- MFMA: 4 k-chunks x 6 M-tiles, B-frags register-resident ----
    f32x4 acc[6] = {};
#pragma unroll
    for (int ch = 0; ch < 4; ++ch) {
#pragma unroll
        for (int mt = 0; mt < 6; ++mt) {
            bf16x8 a0 = *(const bf16x8*)&A_s[(16 * mt + l15) * LP2 + 64 * ch + 8 * lg];
            bf16x8 a1 = *(const bf16x8*)&A_s[(16 * mt + l15) * LP2 + 64 * ch + 32 + 8 * lg];
            acc[mt] = __builtin_amdgcn_mfma_f32_16x16x32_bf16(a0, mreg[2 * ch],     acc[mt], 0, 0, 0);
            acc[mt] = __builtin_amdgcn_mfma_f32_16x16x32_bf16(a1, mreg[2 * ch + 1], acc[mt], 0, 0, 0);
        }
    }

    // relu-sum: lane row = 16mt+4lg+q; c = row>>3, b = row&7.
    // lg<2 -> even slots (c=2mt), lg>=2 -> odd slots (c=2mt+1; mt=5 -> pad).
    const int dg = 16 * w + l15;
    const float mb = M_b[dg];
    float p1[4] = {0, 0, 0, 0}, p2[4] = {0, 0, 0, 0};
#pragma unroll
    for (int mt = 0; mt < 6; ++mt) {
#pragma unroll
        for (int q = 0; q < 4; ++q) {
            float r = fmaxf(acc[mt][q] + mb, 0.0f);
            if (lg < 2) { if (mt == 0) p1[q] = r; else p2[q] += r; }
            else        { if (mt < 5)  p2[q] += r; }
        }
    }
#pragma unroll
    for (int q = 0; q < 4; ++q) {
        float other = __shfl_xor(p2[q], 32);     // pair lg0<->lg2, lg1<->lg3
        if (lg < 2) {
            int b = 4 * lg + q;
            __hip_bfloat16 t1 = __float2bfloat16(10.0f * p1[q]);   // C*relu(Rw)
            __hip_bfloat16 t2 = __float2bfloat16(p2[q] + other);   // sum relu(Rc)
            hws[(size_t)(b0 + b) * 256 + dg]       = *(unsigned short*)&t1;
            hws[(size_t)(b0 + b) * 256 + 128 + dg] = *(unsigned short*)&t2;
        }
    }
}

// ---------------- kernel 2: h @ [U;W]^T + softplus + KL (BT2=32) ----------------
#define BT2  32
#define HLP  264

__global__ __launch_bounds__(512, 4) void bsg_kl(
    const int* __restrict__ x, const float* __restrict__ U_b,
    const float* __restrict__ W_b, const float* __restrict__ pmu,
    const float* __restrict__ psg, const unsigned short* __restrict__ wsr,
    float* __restrict__ out)
{
    __shared__ __align__(16) unsigned short H_s[BT2 * HLP];   // 16896 B
    __shared__ float P_s[BT2 * 8];

    const int tid  = threadIdx.x;
    const int b0   = blockIdx.x * BT2;
    const int w    = tid >> 6;       // wave 0..7 owns d-cols 16w..16w+15
    const int lane = tid & 63;
    const int l15  = lane & 15;
    const int lg   = lane >> 4;
    const int d    = 16 * w + l15;

    // prior gathers issued upfront (x[] L2-hot); consumed only in epilogue
    float pm[2][4], ps[2][4];
#pragma unroll
    for (int mt = 0; mt < 2; ++mt)
#pragma unroll
        for (int q = 0; q < 4; ++q) {
            int xb = x[b0 + 16 * mt + 4 * lg + q];
            pm[mt][q] = pmu[(size_t)xb * DDIM + d];
            ps[mt][q] = psg[(size_t)xb * DDIM + d];
        }

    // h tile copy: 512 threads x 2 x 16B = whole [32][256] tile
    const unsigned short* hws = wsr + WS_H;
#pragma unroll
    for (int s = 0; s < 2; ++s) {
        int it = tid + 512 * s;
        int r = it >> 5, q = it & 31;
        *(uint4*)&H_s[r * HLP + 8 * q] =
            *(const uint4*)&hws[(size_t)(b0 + r) * 256 + 8 * q];
    }
    __syncthreads();

    const unsigned short* UWb = wsr + WS_UW;    // [256][256]: 0..127=U, 128..255=W
    f32x4 acc2[2][2] = {};                      // [mtile][0=mu,1=presig]
#pragma unroll
    for (int ks = 0; ks < 8; ++ks) {
        bf16x8 bu = *(const bf16x8*)&UWb[d * 256 + 32 * ks + 8 * lg];
        bf16x8 bw = *(const bf16x8*)&UWb[(128 + d) * 256 + 32 * ks + 8 * lg];
#pragma unroll
        for (int mt = 0; mt < 2; ++mt) {
            bf16x8 hf = *(const bf16x8*)&H_s[(16 * mt + l15) * HLP + 32 * ks + 8 * lg];
            acc2[mt][0] = __builtin_amdgcn_mfma_f32_16x16x32_bf16(hf, bu, acc2[mt][0], 0, 0, 0);
            acc2[mt][1] = __builtin_amdgcn_mfma_f32_16x16x32_bf16(hf, bw, acc2[mt][1], 0, 0, 0);
        }
    }

    const float ub = U_b[d], wb = W_b[d];
#pragma unroll
    for (int mt = 0; mt < 2; ++mt) {
#pragma unroll
        for (int q = 0; q < 4; ++q) {
            int rb = 16 * mt + 4 * lg + q;      // batch row (C/D: row=4lg+q, col=l15)
            float mu = acc2[mt][0][q] + ub;
            float sg = softplusf(acc2[mt][1][q] + wb);
            float dm = mu - pm[mt][q];
            float p  = ps[mt][q] / sg + dm * dm / sg + logf(sg) - logf(ps[mt][q]);
            p += __shfl_xor(p, 1);
            p += __shfl_xor(p, 2);
            p += __shfl_xor(p, 4);
            p += __shfl_xor(p, 8);
            if (l15 == 0) P_s[rb * 8 + w] = p;
        }
    }
    __syncthreads();
    if (tid < BT2) {
        float s = 0.0f;
#pragma unroll
        for (int k = 0; k < 8; ++k) s += P_s[tid * 8 + k];
        out[b0 + tid] = 0.5f * (s - (float)DDIM);
    }
}

extern "C" void kernel_launch(void* const* d_in, const int* in_sizes, int n_in,
                              void* d_out, int out_size, void* d_ws, size_t ws_size,
                              hipStream_t stream) {
    const int*   x     = (const int*)  d_in[0];
    const int*   ctx   = (const int*)  d_in[1];
    const float* W_emb = (const float*)d_in[2];
    const float* M_w   = (const float*)d_in[3];
    const float* M_b   = (const float*)d_in[4];
    const float* U_w   = (const float*)d_in[5];
    const float* U_b   = (const float*)d_in[6];
    const float* W_w   = (const float*)d_in[7];
    const float* W_b   = (const float*)d_in[8];
    const float* pmu   = (const float*)d_in[9];
    const float* psg   = (const float*)d_in[10];
    float* out = (float*)d_out;
    unsigned short* ws = (unsigned short*)d_ws;   // needs >= 4,325,376 bytes

    bsg_h<<<dim3(8192 / BT1), dim3(512), 0, stream>>>(x, ctx, W_emb, M_w, M_b,
                                                      U_w, W_w, ws, ws + WS_H);
    bsg_kl<<<dim3(8192 / BT2), dim3(512), 0, stream>>>(x, U_b, W_b, pmu, psg,
                                                       ws, out);
}

// Round 19
// 43.988 us; speedup vs baseline: 1.0533x; 1.0277x over previous
//
#include <hip/hip_runtime.h>
#include <hip/hip_bf16.h>
#include <math.h>

// BayesianSkipgram: V=100000, E=256, D=128, B=8192, C=10
// v19 = v15 + bsg_h M-fragment prefetch (single variable):
//   mreg[8] loaded from the L2-hot bf16 ws panel UPFRONT (before idx +
//   gather chain, 8 x 16B, no cvt) instead of in-loop after the barrier —
//   removes the post-barrier L2 dependency from the MFMA critical path.
//   Staging: v15/v16's 2x6 split, ONE barrier. BT1=8.
//   bsg_kl (BT2=32), k_cvt: unchanged from v15.
// ws layout (ushort): M_bf [0,32768), U|W_bf [32768,98304), h [98304,+2M).

#define CTXN  10
#define DDIM  128
#define WS_M   0
#define WS_UW  32768
#define WS_H   98304

typedef short bf16x8 __attribute__((ext_vector_type(8)));
typedef float f32x4  __attribute__((ext_vector_type(4)));

__device__ __forceinline__ uint2 cvt4(float4 v) {
    union { __hip_bfloat162 h2; unsigned u; } a, b;
    a.h2 = __float22bfloat162_rn(make_float2(v.x, v.y));
    b.h2 = __float22bfloat162_rn(make_float2(v.z, v.w));
    return make_uint2(a.u, b.u);
}

__device__ __forceinline__ float softplusf(float v) {
    return fmaxf(v, 0.0f) + log1pf(expf(-fabsf(v)));
}

// ---------------- kernel 0: weight fp32 -> bf16 ----------------
__global__ __launch_bounds__(256) void k_cvt(
    const float* __restrict__ M_w, const float* __restrict__ U_w,
    const float* __restrict__ W_w, unsigned short* __restrict__ ws)
{
    int which = blockIdx.x >> 5;                       // 0:M 1:U 2:W
    int i = ((blockIdx.x & 31) << 8) | threadIdx.x;    // float4 idx 0..8191
    const float* src = (which == 0) ? M_w : (which == 1) ? U_w : W_w;
    float4 v = ((const float4*)src)[i];
    *(uint2*)&ws[which * 32768 + i * 4] = cvt4(v);
}

// ---------------- kernel 1: gather + emb@M_w^T + relu-sum -> h ----------------
#define BT1   8
#define ROWSP 96              // rows r = c*8+b (c=0..10); 88..95 garbage
#define LP2   264             // A row stride (ushort): 528 B

__global__ __launch_bounds__(512, 4) void bsg_h(
    const int* __restrict__ x, const int* __restrict__ ctx,
    const float* __restrict__ W_emb, const float* __restrict__ M_b,
    const unsigned short* __restrict__ wsr, unsigned short* __restrict__ hws)
{
    __shared__ __align__(16) unsigned short A_s[ROWSP * LP2];   // 50688 B
    __shared__ int idx_s[ROWSP];

    const int tid  = threadIdx.x;
    const int b0   = blockIdx.x * BT1;
    const int w    = tid >> 6;       // wave 0..7 owns d-cols 16w..16w+15
    const int lane = tid & 63;
    const int l15  = lane & 15;
    const int lg   = lane >> 4;

    // ---- M-fragments from bf16 ws, issued FIRST (overlap the gather) ----
    const unsigned short* Mb_bf = wsr + WS_M;   // [128][256] bf16
    const int mrow = 16 * w + l15;
    bf16x8 mreg[8];
#pragma unroll
    for (int kk = 0; kk < 8; ++kk)
        mreg[kk] = *(const bf16x8*)&Mb_bf[mrow * 256 + 32 * kk + 8 * lg];

    if (tid < ROWSP) {
        int c = tid >> 3, b = b0 + (tid & 7);
        idx_s[tid] = (c >= 11) ? 0 : ((c == 0) ? x[b] : ctx[b * CTXN + (c - 1)]);
    }
    __syncthreads();

    // ---- staging in 2 groups of 6 (wave-per-row coalescing) ----
    const int rs = tid >> 6;
    const int qs = tid & 63;
    const float4* We = (const float4*)W_emb;
    {
        float4 rr[6];
#pragma unroll
        for (int s = 0; s < 6; ++s)
            rr[s] = We[(size_t)idx_s[rs + 8 * s] * 64 + qs];
#pragma unroll
        for (int s = 0; s < 6; ++s)
            *(uint2*)&A_s[(rs + 8 * s) * LP2 + 4 * qs] = cvt4(rr[s]);
#pragma unroll
        for (int s = 6; s < 12; ++s)
            rr[s - 6] = We[(size_t)idx_s[rs + 8 * s] * 64 + qs];
#pragma unroll
        for (int s = 6; s < 12; ++s)
            *(uint2*)&A_s[(rs + 8 * s) * LP2 + 4 * qs] = cvt4(rr[s - 6]);
    }
    __syncthreads();   // the only phase-1 barrier

    // ---- MFMA: 4 k-chunks x 6 M-tiles, B-frags register-resident ----
    f32x4 acc[6] = {};
#pragma unroll
    for (int ch = 0; ch < 4; ++ch) {
#pragma unroll
        for (int mt = 0; mt < 6; ++mt) {
            bf16x8 a0 = *(const bf16x8*)&A_s[(16 * mt + l15) * LP2 + 64 * ch + 8 * lg];
            bf16x8 a1 = *(const bf16x8*)&A_s[(16 * mt + l15) * LP2 + 64 * ch + 32 + 8 * lg];
            acc[mt] = __builtin_amdgcn_mfma_f32_16x16x32_bf16(a0, mreg[2 * ch],     acc[mt], 0, 0, 0);
            acc[mt] = __builtin_amdgcn_mfma_f32_16x16x32_bf16(a1, mreg[2 * ch + 1], acc[mt], 0, 0, 0);
        }
    }

    // relu-sum: lane row = 16mt+4lg+q; c = row>>3, b = row&7.
    // lg<2 -> even slots (c=2mt), lg>=2 -> odd slots (c=2mt+1; mt=5 -> pad).
    const int dg = 16 * w + l15;
    const float mb = M_b[dg];
    float p1[4] = {0, 0, 0, 0}, p2[4] = {0, 0, 0, 0};
#pragma unroll
    for (int mt = 0; mt < 6; ++mt) {
#pragma unroll
        for (int q = 0; q < 4; ++q) {
            float r = fmaxf(acc[mt][q] + mb, 0.0f);
            if (lg < 2) { if (mt == 0) p1[q] = r; else p2[q] += r; }
            else        { if (mt < 5)  p2[q] += r; }
        }
    }
#pragma unroll
    for (int q = 0; q < 4; ++q) {
        float other = __shfl_xor(p2[q], 32);     // pair lg0<->lg2, lg1<->lg3
        if (lg < 2) {
            int b = 4 * lg + q;
            __hip_bfloat16 t1 = __float2bfloat16(10.0f * p1[q]);   // C*relu(Rw)
            __hip_bfloat16 t2 = __float2bfloat16(p2[q] + other);   // sum relu(Rc)
            hws[(size_t)(b0 + b) * 256 + dg]       = *(unsigned short*)&t1;
            hws[(size_t)(b0 + b) * 256 + 128 + dg] = *(unsigned short*)&t2;
        }
    }
}

// ---------------- kernel 2: h @ [U;W]^T + softplus + KL (BT2=32) ----------------
#define BT2  32
#define HLP  264

__global__ __launch_bounds__(512, 4) void bsg_kl(
    const int* __restrict__ x, const float* __restrict__ U_b,
    const float* __restrict__ W_b, const float* __restrict__ pmu,
    const float* __restrict__ psg, const unsigned short* __restrict__ wsr,
    float* __restrict__ out)
{
    __shared__ __align__(16) unsigned short H_s[BT2 * HLP];   // 16896 B
    __shared__ float P_s[BT2 * 8];

    const int tid  = threadIdx.x;
    const int b0   = blockIdx.x * BT2;
    const int w    = tid >> 6;       // wave 0..7 owns d-cols 16w..16w+15
    const int lane = tid & 63;
    const int l15  = lane & 15;
    const int lg   = lane >> 4;
    const int d    = 16 * w + l15;

    // prior gathers issued upfront (x[] L2-hot); consumed only in epilogue
    float pm[2][4], ps[2][4];
#pragma unroll
    for (int mt = 0; mt < 2; ++mt)
#pragma unroll
        for (int q = 0; q < 4; ++q) {
            int xb = x[b0 + 16 * mt + 4 * lg + q];
            pm[mt][q] = pmu[(size_t)xb * DDIM + d];
            ps[mt][q] = psg[(size_t)xb * DDIM + d];
        }

    // h tile copy: 512 threads x 2 x 16B = whole [32][256] tile
    const unsigned short* hws = wsr + WS_H;
#pragma unroll
    for (int s = 0; s < 2; ++s) {
        int it = tid + 512 * s;
        int r = it >> 5, q = it & 31;
        *(uint4*)&H_s[r * HLP + 8 * q] =
            *(const uint4*)&hws[(size_t)(b0 + r) * 256 + 8 * q];
    }
    __syncthreads();

    const unsigned short* UWb = wsr + WS_UW;    // [256][256]: 0..127=U, 128..255=W
    f32x4 acc2[2][2] = {};                      // [mtile][0=mu,1=presig]
#pragma unroll
    for (int ks = 0; ks < 8; ++ks) {
        bf16x8 bu = *(const bf16x8*)&UWb[d * 256 + 32 * ks + 8 * lg];
        bf16x8 bw = *(const bf16x8*)&UWb[(128 + d) * 256 + 32 * ks + 8 * lg];
#pragma unroll
        for (int mt = 0; mt < 2; ++mt) {
            bf16x8 hf = *(const bf16x8*)&H_s[(16 * mt + l15) * HLP + 32 * ks + 8 * lg];
            acc2[mt][0] = __builtin_amdgcn_mfma_f32_16x16x32_bf16(hf, bu, acc2[mt][0], 0, 0, 0);
            acc2[mt][1] = __builtin_amdgcn_mfma_f32_16x16x32_bf16(hf, bw, acc2[mt][1], 0, 0, 0);
        }
    }

    const float ub = U_b[d], wb = W_b[d];
#pragma unroll
    for (int mt = 0; mt < 2; ++mt) {
#pragma unroll
        for (int q = 0; q < 4; ++q) {
            int rb = 16 * mt + 4 * lg + q;      // batch row (C/D: row=4lg+q, col=l15)
            float mu = acc2[mt][0][q] + ub;
            float sg = softplusf(acc2[mt][1][q] + wb);
            float dm = mu - pm[mt][q];
            float p  = ps[mt][q] / sg + dm * dm / sg + logf(sg) - logf(ps[mt][q]);
            p += __shfl_xor(p, 1);
            p += __shfl_xor(p, 2);
            p += __shfl_xor(p, 4);
            p += __shfl_xor(p, 8);
            if (l15 == 0) P_s[rb * 8 + w] = p;
        }
    }
    __syncthreads();
    if (tid < BT2) {
        float s = 0.0f;
#pragma unroll
        for (int k = 0; k < 8; ++k) s += P_s[tid * 8 + k];
        out[b0 + tid] = 0.5f * (s - (float)DDIM);
    }
}

extern "C" void kernel_launch(void* const* d_in, const int* in_sizes, int n_in,
                              void* d_out, int out_size, void* d_ws, size_t ws_size,
                              hipStream_t stream) {
    const int*   x     = (const int*)  d_in[0];
    const int*   ctx   = (const int*)  d_in[1];
    const float* W_emb = (const float*)d_in[2];
    const float* M_w   = (const float*)d_in[3];
    const float* M_b   = (const float*)d_in[4];
    const float* U_w   = (const float*)d_in[5];
    const float* U_b   = (const float*)d_in[6];
    const float* W_w   = (const float*)d_in[7];
    const float* W_b   = (const float*)d_in[8];
    const float* pmu   = (const float*)d_in[9];
    const float* psg   = (const float*)d_in[10];
    float* out = (float*)d_out;
    unsigned short* ws = (unsigned short*)d_ws;   // needs >= 4,390,912 bytes

    k_cvt<<<dim3(96), dim3(256), 0, stream>>>(M_w, U_w, W_w, ws);
    bsg_h<<<dim3(8192 / BT1), dim3(512), 0, stream>>>(x, ctx, W_emb, M_b,
                                                      ws, ws + WS_H);
    bsg_kl<<<dim3(8192 / BT2), dim3(512), 0, stream>>>(x, U_b, W_b, pmu, psg,
                                                       ws, out);
}

// Round 20
// 41.540 us; speedup vs baseline: 1.1154x; 1.0589x over previous
//
#include <hip/hip_runtime.h>
#include <hip/hip_bf16.h>
#include <math.h>

// BayesianSkipgram: V=100000, E=256, D=128, B=8192, C=10
// FINAL (v15, champion @ 41.50us): three kernels.
//   k_cvt : M_w/U_w/W_w fp32 -> bf16 into ws (192 KB).
//   bsg_h : gathered emb @ M_w^T + relu-sum -> h[8192,256] bf16 in ws.
//           BT=8, 512 thr, 1024 blocks (3/CU, LDS-limited). Single-shot
//           staging: 12 wave-per-row coalesced 1KB loads upfront (max MLP),
//           ONE barrier; M-frags loaded in-loop from L2-hot bf16 panel.
//   bsg_kl: h @ [U;W]^T + softplus + prior-gather + KL. BT=32 (256 blocks),
//           2 M-tiles/wave, priors hoisted to kernel start.
// Tried & rejected: fusion (46-49), vocab-precompute (54), reg-direct gather
// (74), fp32 weight paths (45-52), BT1=4/16 (46), deeper pipelines (42-48),
// mreg hoist (44). Latency-structure floor of the scattered gather.
// ws layout (ushort): M_bf [0,32768), U|W_bf [32768,98304), h [98304,+2M).

#define CTXN  10
#define DDIM  128
#define WS_M   0
#define WS_UW  32768
#define WS_H   98304

typedef short bf16x8 __attribute__((ext_vector_type(8)));
typedef float f32x4  __attribute__((ext_vector_type(4)));

__device__ __forceinline__ uint2 cvt4(float4 v) {
    union { __hip_bfloat162 h2; unsigned u; } a, b;
    a.h2 = __float22bfloat162_rn(make_float2(v.x, v.y));
    b.h2 = __float22bfloat162_rn(make_float2(v.z, v.w));
    return make_uint2(a.u, b.u);
}

__device__ __forceinline__ float softplusf(float v) {
    return fmaxf(v, 0.0f) + log1pf(expf(-fabsf(v)));
}

// ---------------- kernel 0: weight fp32 -> bf16 ----------------
__global__ __launch_bounds__(256) void k_cvt(
    const float* __restrict__ M_w, const float* __restrict__ U_w,
    const float* __restrict__ W_w, unsigned short* __restrict__ ws)
{
    int which = blockIdx.x >> 5;                       // 0:M 1:U 2:W
    int i = ((blockIdx.x & 31) << 8) | threadIdx.x;    // float4 idx 0..8191
    const float* src = (which == 0) ? M_w : (which == 1) ? U_w : W_w;
    float4 v = ((const float4*)src)[i];
    *(uint2*)&ws[which * 32768 + i * 4] = cvt4(v);
}

// ---------------- kernel 1: gather + emb@M_w^T + relu-sum -> h ----------------
#define BT1   8
#define ROWSP 96              // LDS rows 0..87 staged (r = c*8+b); 88..95 garbage
#define LP2   264             // A row stride (ushort): 528 B -> 2-way bank alias (free)

__global__ __launch_bounds__(512, 4) void bsg_h(
    const int* __restrict__ x, const int* __restrict__ ctx,
    const float* __restrict__ W_emb, const float* __restrict__ M_b,
    const unsigned short* __restrict__ wsr, unsigned short* __restrict__ hws)
{
    __shared__ __align__(16) unsigned short A_s[ROWSP * LP2];   // 50688 B
    __shared__ int idx_s[ROWSP];

    const int tid  = threadIdx.x;
    const int b0   = blockIdx.x * BT1;
    const int w    = tid >> 6;       // wave 0..7 owns d-cols 16w..16w+15
    const int lane = tid & 63;
    const int l15  = lane & 15;
    const int lg   = lane >> 4;

    if (tid < ROWSP) {
        int c = tid >> 3, b = b0 + (tid & 7);
        idx_s[tid] = (c >= 11) ? 0 : ((c == 0) ? x[b] : ctx[b * CTXN + (c - 1)]);
    }
    __syncthreads();

    // ---- single-shot staging: 12 steps, wave-per-row perfect coalescing ----
    const int rs = tid >> 6;
    const int qs = tid & 63;
    const float4* We = (const float4*)W_emb;

    float4 rr[12];
#pragma unroll
    for (int s = 0; s < 12; ++s)
        rr[s] = We[(size_t)idx_s[rs + 8 * s] * 64 + qs];
#pragma unroll
    for (int s = 0; s < 12; ++s)
        *(uint2*)&A_s[(rs + 8 * s) * LP2 + 4 * qs] = cvt4(rr[s]);
    __syncthreads();   // the only phase-1 barrier

    // ---- MFMA: 4 k-chunks x 6 M-tiles, M-frags from L2-hot bf16 ws ----
    const unsigned short* Mb_bf = wsr + WS_M;   // [128][256] bf16
    const int mrow = 16 * w + l15;
    f32x4 acc[6] = {};
#pragma unroll
    for (int ch = 0; ch < 4; ++ch) {
        bf16x8 m0 = *(const bf16x8*)&Mb_bf[mrow * 256 + 64 * ch + 8 * lg];
        bf16x8 m1 = *(const bf16x8*)&Mb_bf[mrow * 256 + 64 * ch + 32 + 8 * lg];
#pragma unroll
        for (int mt = 0; mt < 6; ++mt) {
            bf16x8 a0 = *(const bf16x8*)&A_s[(16 * mt + l15) * LP2 + 64 * ch + 8 * lg];
            bf16x8 a1 = *(const bf16x8*)&A_s[(16 * mt + l15) * LP2 + 64 * ch + 32 + 8 * lg];
            acc[mt] = __builtin_amdgcn_mfma_f32_16x16x32_bf16(a0, m0, acc[mt], 0, 0, 0);
            acc[mt] = __builtin_amdgcn_mfma_f32_16x16x32_bf16(a1, m1, acc[mt], 0, 0, 0);
        }
    }

    // relu-sum: lane row = 16mt+4lg+q; c = row>>3, b = row&7.
    // lg<2 -> even slots (c=2mt), lg>=2 -> odd slots (c=2mt+1; mt=5 -> pad).
    const int dg = 16 * w + l15;
    const float mb = M_b[dg];
    float p1[4] = {0, 0, 0, 0}, p2[4] = {0, 0, 0, 0};
#pragma unroll
    for (int mt = 0; mt < 6; ++mt) {
#pragma unroll
        for (int q = 0; q < 4; ++q) {
            float r = fmaxf(acc[mt][q] + mb, 0.0f);
            if (lg < 2) { if (mt == 0) p1[q] = r; else p2[q] += r; }
            else        { if (mt < 5)  p2[q] += r; }
        }
    }
#pragma unroll
    for (int q = 0; q < 4; ++q) {
        float other = __shfl_xor(p2[q], 32);     // pair lg0<->lg2, lg1<->lg3
        if (lg < 2) {
            int b = 4 * lg + q;
            __hip_bfloat16 t1 = __float2bfloat16(10.0f * p1[q]);   // C*relu(Rw)
            __hip_bfloat16 t2 = __float2bfloat16(p2[q] + other);   // sum relu(Rc)
            hws[(size_t)(b0 + b) * 256 + dg]       = *(unsigned short*)&t1;
            hws[(size_t)(b0 + b) * 256 + 128 + dg] = *(unsigned short*)&t2;
        }
    }
}

// ---------------- kernel 2: h @ [U;W]^T + softplus + KL (BT2=32) ----------------
#define BT2  32
#define HLP  264

__global__ __launch_bounds__(512, 4) void bsg_kl(
    const int* __restrict__ x, const float* __restrict__ U_b,
    const float* __restrict__ W_b, const float* __restrict__ pmu,
    const float* __restrict__ psg, const unsigned short* __restrict__ wsr,
    float* __restrict__ out)
{
    __shared__ __align__(16) unsigned short H_s[BT2 * HLP];   // 16896 B
    __shared__ float P_s[BT2 * 8];

    const int tid  = threadIdx.x;
    const int b0   = blockIdx.x * BT2;
    const int w    = tid >> 6;       // wave 0..7 owns d-cols 16w..16w+15
    const int lane = tid & 63;
    const int l15  = lane & 15;
    const int lg   = lane >> 4;
    const int d    = 16 * w + l15;

    // prior gathers issued upfront (x[] L2-hot); consumed only in epilogue
    float pm[2][4], ps[2][4];
#pragma unroll
    for (int mt = 0; mt < 2; ++mt)
#pragma unroll
        for (int q = 0; q < 4; ++q) {
            int xb = x[b0 + 16 * mt + 4 * lg + q];
            pm[mt][q] = pmu[(size_t)xb * DDIM + d];
            ps[mt][q] = psg[(size_t)xb * DDIM + d];
        }

    // h tile copy: 512 threads x 2 x 16B = whole [32][256] tile
    const unsigned short* hws = wsr + WS_H;
#pragma unroll
    for (int s = 0; s < 2; ++s) {
        int it = tid + 512 * s;
        int r = it >> 5, q = it & 31;
        *(uint4*)&H_s[r * HLP + 8 * q] =
            *(const uint4*)&hws[(size_t)(b0 + r) * 256 + 8 * q];
    }
    __syncthreads();

    const unsigned short* UWb = wsr + WS_UW;    // [256][256]: 0..127=U, 128..255=W
    f32x4 acc2[2][2] = {};                      // [mtile][0=mu,1=presig]
#pragma unroll
    for (int ks = 0; ks < 8; ++ks) {
        bf16x8 bu = *(const bf16x8*)&UWb[d * 256 + 32 * ks + 8 * lg];
        bf16x8 bw = *(const bf16x8*)&UWb[(128 + d) * 256 + 32 * ks + 8 * lg];
#pragma unroll
        for (int mt = 0; mt < 2; ++mt) {
            bf16x8 hf = *(const bf16x8*)&H_s[(16 * mt + l15) * HLP + 32 * ks + 8 * lg];
            acc2[mt][0] = __builtin_amdgcn_mfma_f32_16x16x32_bf16(hf, bu, acc2[mt][0], 0, 0, 0);
            acc2[mt][1] = __builtin_amdgcn_mfma_f32_16x16x32_bf16(hf, bw, acc2[mt][1], 0, 0, 0);
        }
    }

    const float ub = U_b[d], wb = W_b[d];
#pragma unroll
    for (int mt = 0; mt < 2; ++mt) {
#pragma unroll
        for (int q = 0; q < 4; ++q) {
            int rb = 16 * mt + 4 * lg + q;      // batch row (C/D: row=4lg+q, col=l15)
            float mu = acc2[mt][0][q] + ub;
            float sg = softplusf(acc2[mt][1][q] + wb);
            float dm = mu - pm[mt][q];
            float p  = ps[mt][q] / sg + dm * dm / sg + logf(sg) - logf(ps[mt][q]);
            p += __shfl_xor(p, 1);
            p += __shfl_xor(p, 2);
            p += __shfl_xor(p, 4);
            p += __shfl_xor(p, 8);
            if (l15 == 0) P_s[rb * 8 + w] = p;
        }
    }
    __syncthreads();
    if (tid < BT2) {
        float s = 0.0f;
#pragma unroll
        for (int k = 0; k < 8; ++k) s += P_s[tid * 8 + k];
        out[b0 + tid] = 0.5f * (s - (float)DDIM);
    }
}

extern "C" void kernel_launch(void* const* d_in, const int* in_sizes, int n_in,
                              void* d_out, int out_size, void* d_ws, size_t ws_size,
                              hipStream_t stream) {
    const int*   x     = (const int*)  d_in[0];
    const int*   ctx   = (const int*)  d_in[1];
    const float* W_emb = (const float*)d_in[2];
    const float* M_w   = (const float*)d_in[3];
    const float* M_b   = (const float*)d_in[4];
    const float* U_w   = (const float*)d_in[5];
    const float* U_b   = (const float*)d_in[6];
    const float* W_w   = (const float*)d_in[7];
    const float* W_b   = (const float*)d_in[8];
    const float* pmu   = (const float*)d_in[9];
    const float* psg   = (const float*)d_in[10];
    float* out = (float*)d_out;
    unsigned short* ws = (unsigned short*)d_ws;   // needs >= 4,390,912 bytes

    k_cvt<<<dim3(96), dim3(256), 0, stream>>>(M_w, U_w, W_w, ws);
    bsg_h<<<dim3(8192 / BT1), dim3(512), 0, stream>>>(x, ctx, W_emb, M_b,
                                                      ws, ws + WS_H);
    bsg_kl<<<dim3(8192 / BT2), dim3(512), 0, stream>>>(x, U_b, W_b, pmu, psg,
                                                       ws, out);
}